// Round 1
// baseline (1086.299 us; speedup 1.0000x reference)
//
#include <hip/hip_runtime.h>
#include <math.h>

#define BATCH 8
#define NPTS  1024
#define DIM   1024
#define HID   64
#define KNN   20
#define NMAT  16

__device__ __forceinline__ const float* mat_base(const float* f1, const float* f2, int m) {
    return (m < BATCH) ? (f1 + (size_t)m * NPTS * DIM)
                       : (f2 + (size_t)(m - BATCH) * NPTS * DIM);
}

// ---------------- K1: squared norms (one wave per row) ----------------
__global__ __launch_bounds__(256) void sqnorm_kernel(const float* __restrict__ f1,
                                                     const float* __restrict__ f2,
                                                     float* __restrict__ sq) {
    int tid = threadIdx.x;
    int wave = tid >> 6, lane = tid & 63;
    int row = blockIdx.x * 4 + wave;              // 0..16383 = m*NPTS + i
    int m = row >> 10, i = row & (NPTS - 1);
    const float* fr = mat_base(f1, f2, m) + (size_t)i * DIM;
    float s = 0.f;
    #pragma unroll
    for (int t = 0; t < DIM / 64; ++t) {
        float v = fr[lane + t * 64];
        s += v * v;
    }
    #pragma unroll
    for (int off = 32; off > 0; off >>= 1) s += __shfl_down(s, off);
    if (lane == 0) sq[row] = s;
}

// ---------------- K2: Gram -> squared distances (fp32 SGEMM, 128x128x16 tiles) ----------------
__global__ __launch_bounds__(256) void gram_kernel(const float* __restrict__ f1,
                                                   const float* __restrict__ f2,
                                                   const float* __restrict__ sq,
                                                   float* __restrict__ dist) {
    int bid = blockIdx.x;
    int m = bid >> 6;              // 64 tiles per matrix
    int tile = bid & 63;
    int ti = (tile >> 3) << 7;
    int tj = (tile & 7) << 7;
    const float* f = mat_base(f1, f2, m);
    __shared__ float As[16][136];   // [k][row], pitch 136 (544B, 16B-aligned rows)
    __shared__ float Bs[16][136];
    int tid = threadIdx.x;
    int ty = tid >> 4, tx = tid & 15;
    float acc[8][8];
    #pragma unroll
    for (int i = 0; i < 8; ++i)
        #pragma unroll
        for (int j = 0; j < 8; ++j) acc[i][j] = 0.f;

    for (int kk = 0; kk < DIM; kk += 16) {
        #pragma unroll
        for (int ldi = 0; ldi < 2; ++ldi) {
            int lin = tid + ldi * 256;       // 512 float4 units
            int r = lin >> 2;                // 0..127
            int c = (lin & 3) * 4;           // 0,4,8,12
            float4 a = *(const float4*)&f[(size_t)(ti + r) * DIM + kk + c];
            As[c + 0][r] = a.x; As[c + 1][r] = a.y; As[c + 2][r] = a.z; As[c + 3][r] = a.w;
            float4 b = *(const float4*)&f[(size_t)(tj + r) * DIM + kk + c];
            Bs[c + 0][r] = b.x; Bs[c + 1][r] = b.y; Bs[c + 2][r] = b.z; Bs[c + 3][r] = b.w;
        }
        __syncthreads();
        #pragma unroll
        for (int k = 0; k < 16; ++k) {
            float av[8], bv[8];
            *(float4*)&av[0] = *(const float4*)&As[k][ty * 8];
            *(float4*)&av[4] = *(const float4*)&As[k][ty * 8 + 4];
            *(float4*)&bv[0] = *(const float4*)&Bs[k][tx * 8];
            *(float4*)&bv[4] = *(const float4*)&Bs[k][tx * 8 + 4];
            #pragma unroll
            for (int ii = 0; ii < 8; ++ii)
                #pragma unroll
                for (int jj = 0; jj < 8; ++jj)
                    acc[ii][jj] += av[ii] * bv[jj];
        }
        __syncthreads();
    }
    const float* sqm = sq + m * NPTS;
    float sqj[8];
    #pragma unroll
    for (int jj = 0; jj < 8; ++jj) sqj[jj] = sqm[tj + tx * 8 + jj];
    #pragma unroll
    for (int ii = 0; ii < 8; ++ii) {
        int r = ti + ty * 8 + ii;
        float si = sqm[r];
        float o[8];
        #pragma unroll
        for (int jj = 0; jj < 8; ++jj) {
            int c = tj + tx * 8 + jj;
            float v = si + sqj[jj] - 2.f * acc[ii][jj];
            if (r == c) v += 1e10f;            // exclude self, matches reference
            o[jj] = v;
        }
        float* dst = dist + ((size_t)m * NPTS + r) * NPTS + tj + tx * 8;
        *(float4*)&dst[0] = *(float4*)&o[0];
        *(float4*)&dst[4] = *(float4*)&o[4];
    }
}

// ---------------- K3: top-k (k=20 smallest) per row, iterative select-min ----------------
__global__ __launch_bounds__(256) void topk_kernel(const float* __restrict__ dist,
                                                   int* __restrict__ knn_idx) {
    int row = blockIdx.x;                        // m*NPTS + i
    const float* d = dist + (size_t)row * NPTS;
    __shared__ float vals[NPTS];
    __shared__ float cv[4];
    __shared__ int ci[4];
    int tid = threadIdx.x;
    #pragma unroll
    for (int s = 0; s < 4; ++s) vals[tid + s * 256] = d[tid + s * 256];
    __syncthreads();
    for (int sel = 0; sel < KNN; ++sel) {
        float bv = 3e38f; int bi = NPTS;
        #pragma unroll
        for (int s = 0; s < 4; ++s) {
            int j = tid + s * 256;
            float v = vals[j];
            if (v < bv) { bv = v; bi = j; }      // j strictly increases: ties keep lower idx
        }
        #pragma unroll
        for (int off = 32; off > 0; off >>= 1) {
            float ov = __shfl_down(bv, off);
            int   oi = __shfl_down(bi, off);
            if (ov < bv || (ov == bv && oi < bi)) { bv = ov; bi = oi; }
        }
        if ((tid & 63) == 0) { cv[tid >> 6] = bv; ci[tid >> 6] = bi; }
        __syncthreads();
        if (tid == 0) {
            float fv = cv[0]; int fi = ci[0];
            #pragma unroll
            for (int w = 1; w < 4; ++w)
                if (cv[w] < fv || (cv[w] == fv && ci[w] < fi)) { fv = cv[w]; fi = ci[w]; }
            knn_idx[(size_t)row * KNN + sel] = fi;
            vals[fi] = 3e38f;                    // larger than any real dist (incl. 1e10 diag)
        }
        __syncthreads();
    }
}

// ---------------- K4a: x + sum of neighbor features (D=1024) ----------------
__global__ __launch_bounds__(256) void hsum_big_kernel(const float* __restrict__ f1,
                                                       const float* __restrict__ f2,
                                                       const int* __restrict__ knn_idx,
                                                       float* __restrict__ hsum) {
    int row = blockIdx.x;
    int m = row >> 10, i = row & (NPTS - 1);
    const float* f = mat_base(f1, f2, m);
    __shared__ int nb[KNN];
    int tid = threadIdx.x;
    if (tid < KNN) nb[tid] = knn_idx[(size_t)row * KNN + tid];
    __syncthreads();
    int c = tid * 4;
    float4 acc = *(const float4*)&f[(size_t)i * DIM + c];
    #pragma unroll
    for (int t = 0; t < KNN; ++t) {
        float4 v = *(const float4*)&f[(size_t)nb[t] * DIM + c];
        acc.x += v.x; acc.y += v.y; acc.z += v.z; acc.w += v.w;
    }
    *(float4*)&hsum[(size_t)row * DIM + c] = acc;
}

// ---------------- K5a: x + sum of neighbor features (H=64), one wave per row ----------------
__global__ __launch_bounds__(256) void hsum_small_kernel(const float* __restrict__ h,
                                                         const int* __restrict__ knn_idx,
                                                         float* __restrict__ outp) {
    int tid = threadIdx.x;
    int wave = tid >> 6, lane = tid & 63;
    int row = blockIdx.x * 4 + wave;
    int m = row >> 10;
    const int* nb = knn_idx + (size_t)row * KNN;
    const float* hm = h + (size_t)m * NPTS * HID;
    float acc = h[(size_t)row * HID + lane];
    #pragma unroll
    for (int t = 0; t < KNN; ++t)
        acc += hm[(size_t)nb[t] * HID + lane];
    outp[(size_t)row * HID + lane] = acc;
}

// ---------------- MLP GEMM: C[i][h] = act(sum_d A[i][d]*W[d][h] + b[h]) ----------------
template <int DIN, bool RELU>
__global__ __launch_bounds__(256) void mlp_gemm_kernel(const float* __restrict__ A,
                                                       const float* __restrict__ W,
                                                       const float* __restrict__ bias,
                                                       float* __restrict__ C) {
    int row0 = blockIdx.x * 64;
    __shared__ float As[64][20];    // pitch 20 (80B, 16B-aligned)
    __shared__ float Ws[16][HID];
    int tid = threadIdx.x;
    int ty = tid >> 4, tx = tid & 15;
    float acc[4][4];
    #pragma unroll
    for (int i = 0; i < 4; ++i)
        #pragma unroll
        for (int j = 0; j < 4; ++j) acc[i][j] = 0.f;
    for (int kk = 0; kk < DIN; kk += 16) {
        {
            int r = tid >> 2, c = (tid & 3) * 4;
            *(float4*)&As[r][c] = *(const float4*)&A[(size_t)(row0 + r) * DIN + kk + c];
        }
        {
            int d = tid >> 4, hh = (tid & 15) * 4;
            *(float4*)&Ws[d][hh] = *(const float4*)&W[(size_t)(kk + d) * HID + hh];
        }
        __syncthreads();
        #pragma unroll
        for (int k = 0; k < 16; ++k) {
            float a[4];
            #pragma unroll
            for (int ii = 0; ii < 4; ++ii) a[ii] = As[ty * 4 + ii][k];
            float4 w = *(const float4*)&Ws[k][tx * 4];
            #pragma unroll
            for (int ii = 0; ii < 4; ++ii) {
                acc[ii][0] += a[ii] * w.x;
                acc[ii][1] += a[ii] * w.y;
                acc[ii][2] += a[ii] * w.z;
                acc[ii][3] += a[ii] * w.w;
            }
        }
        __syncthreads();
    }
    #pragma unroll
    for (int ii = 0; ii < 4; ++ii) {
        int r = row0 + ty * 4 + ii;
        float o[4];
        #pragma unroll
        for (int jj = 0; jj < 4; ++jj) {
            float v = acc[ii][jj] + bias[tx * 4 + jj];
            if (RELU) v = fmaxf(v, 0.f);
            o[jj] = v;
        }
        *(float4*)&C[(size_t)r * HID + tx * 4] = *(float4*)&o[0];
    }
}

// ---------------- K6a: sim = z1 @ z2^T (64x64 tiles, K=64) ----------------
__global__ __launch_bounds__(256) void sim_kernel(const float* __restrict__ z,
                                                  float* __restrict__ logits) {
    int bid = blockIdx.x;
    int b = bid >> 8;
    int tile = bid & 255;
    int ti = (tile >> 4) << 6;
    int tj = (tile & 15) << 6;
    const float* z1 = z + (size_t)b * NPTS * HID;
    const float* z2 = z + (size_t)(BATCH + b) * NPTS * HID;
    __shared__ float Z1[64][68];    // pitch 68: 2-way max bank conflict, 16B-aligned
    __shared__ float Z2[64][68];
    int tid = threadIdx.x;
    #pragma unroll
    for (int i = 0; i < 4; ++i) {
        int l = tid + i * 256;
        int r = l >> 4, c = (l & 15) * 4;
        *(float4*)&Z1[r][c] = *(const float4*)&z1[(size_t)(ti + r) * HID + c];
        *(float4*)&Z2[r][c] = *(const float4*)&z2[(size_t)(tj + r) * HID + c];
    }
    __syncthreads();
    int ty = tid >> 4, tx = tid & 15;
    float acc[4][4];
    #pragma unroll
    for (int i = 0; i < 4; ++i)
        #pragma unroll
        for (int j = 0; j < 4; ++j) acc[i][j] = 0.f;
    #pragma unroll
    for (int h = 0; h < HID; ++h) {
        float a[4], bb[4];
        #pragma unroll
        for (int ii = 0; ii < 4; ++ii) { a[ii] = Z1[ty * 4 + ii][h]; bb[ii] = Z2[tx * 4 + ii][h]; }
        #pragma unroll
        for (int ii = 0; ii < 4; ++ii)
            #pragma unroll
            for (int jj = 0; jj < 4; ++jj)
                acc[ii][jj] += a[ii] * bb[jj];
    }
    #pragma unroll
    for (int ii = 0; ii < 4; ++ii) {
        float* dst = logits + ((size_t)b * NPTS + ti + ty * 4 + ii) * NPTS + tj + tx * 4;
        *(float4*)&dst[0] = *(float4*)&acc[ii][0];
    }
}

// ---------------- K6b: row softmax ----------------
__global__ __launch_bounds__(256) void softmax_kernel(const float* __restrict__ logits,
                                                      float* __restrict__ out) {
    int row = blockIdx.x;                         // 0..8191
    const float* L = logits + (size_t)row * NPTS;
    __shared__ float buf[NPTS];
    __shared__ float red[8];
    int tid = threadIdx.x;
    int wave = tid >> 6, lane = tid & 63;
    float mx = -3e38f;
    #pragma unroll
    for (int s = 0; s < 4; ++s) {
        float v = L[tid + s * 256];
        buf[tid + s * 256] = v;
        mx = fmaxf(mx, v);
    }
    #pragma unroll
    for (int off = 32; off > 0; off >>= 1) mx = fmaxf(mx, __shfl_down(mx, off));
    if (lane == 0) red[wave] = mx;
    __syncthreads();
    mx = fmaxf(fmaxf(red[0], red[1]), fmaxf(red[2], red[3]));
    float sum = 0.f;
    #pragma unroll
    for (int s = 0; s < 4; ++s) {
        float e = expf(buf[tid + s * 256] - mx);
        buf[tid + s * 256] = e;
        sum += e;
    }
    #pragma unroll
    for (int off = 32; off > 0; off >>= 1) sum += __shfl_down(sum, off);
    if (lane == 0) red[4 + wave] = sum;
    __syncthreads();
    float inv = 1.f / (red[4] + red[5] + red[6] + red[7]);
    #pragma unroll
    for (int s = 0; s < 4; ++s)
        out[(size_t)row * NPTS + tid + s * 256] = buf[tid + s * 256] * inv;
}

extern "C" void kernel_launch(void* const* d_in, const int* in_sizes, int n_in,
                              void* d_out, int out_size, void* d_ws, size_t ws_size,
                              hipStream_t stream) {
    const float* f1  = (const float*)d_in[0];
    const float* f2  = (const float*)d_in[1];
    const float* W1a = (const float*)d_in[2];
    const float* b1a = (const float*)d_in[3];
    const float* W2a = (const float*)d_in[4];
    const float* b2a = (const float*)d_in[5];
    const float* W1b = (const float*)d_in[6];
    const float* b1b = (const float*)d_in[7];
    const float* W2b = (const float*)d_in[8];
    const float* b2b = (const float*)d_in[9];
    float* out = (float*)d_out;

    // workspace layout (floats); dist area (67MB) reused: dist -> hsum -> sim logits
    float* ws   = (float*)d_ws;
    float* dist = ws;                                        // 16*1024*1024
    float* sq   = ws + (size_t)NMAT * NPTS * NPTS;           // 16*1024
    int*   kidx = (int*)(sq + NMAT * NPTS);                  // 16*1024*20 ints
    float* bufA = (float*)(kidx + NMAT * NPTS * KNN);        // 16*1024*64
    float* bufB = bufA + (size_t)NMAT * NPTS * HID;          // 16*1024*64

    sqnorm_kernel<<<NMAT * NPTS / 4, 256, 0, stream>>>(f1, f2, sq);
    gram_kernel<<<NMAT * 64, 256, 0, stream>>>(f1, f2, sq, dist);
    topk_kernel<<<NMAT * NPTS, 256, 0, stream>>>(dist, kidx);
    hsum_big_kernel<<<NMAT * NPTS, 256, 0, stream>>>(f1, f2, kidx, dist);       // dist area := hsum
    mlp_gemm_kernel<DIM, true><<<NMAT * NPTS / 64, 256, 0, stream>>>(dist, W1a, b1a, bufA);   // t1
    mlp_gemm_kernel<HID, false><<<NMAT * NPTS / 64, 256, 0, stream>>>(bufA, W2a, b2a, bufB);  // h1
    hsum_small_kernel<<<NMAT * NPTS / 4, 256, 0, stream>>>(bufB, kidx, bufA);                 // hsum2
    mlp_gemm_kernel<HID, true><<<NMAT * NPTS / 64, 256, 0, stream>>>(bufA, W1b, b1b, bufB);   // t2
    mlp_gemm_kernel<HID, false><<<NMAT * NPTS / 64, 256, 0, stream>>>(bufB, W2b, b2b, bufA);  // z
    sim_kernel<<<BATCH * 256, 256, 0, stream>>>(bufA, dist);                    // dist area := logits
    softmax_kernel<<<BATCH * NPTS, 256, 0, stream>>>(dist, out);
}

// Round 2
// 871.124 us; speedup vs baseline: 1.2470x; 1.2470x over previous
//
#include <hip/hip_runtime.h>
#include <hip/hip_bf16.h>
#include <math.h>

#define BATCH 8
#define NPTS  1024
#define DIM   1024
#define HID   64
#define KNN   20
#define NMAT  16

typedef __attribute__((ext_vector_type(8))) short short8;
typedef __attribute__((ext_vector_type(4))) float floatx4;

__device__ __forceinline__ const float* mat_base(const float* f1, const float* f2, int m) {
    return (m < BATCH) ? (f1 + (size_t)m * NPTS * DIM)
                       : (f2 + (size_t)(m - BATCH) * NPTS * DIM);
}

__device__ __forceinline__ unsigned short f2bf_bits(float v) {
    __hip_bfloat16 h = __float2bfloat16(v);   // RNE
    return *(unsigned short*)&h;
}
__device__ __forceinline__ float bfbits2f(unsigned short b) {
    union { unsigned u; float f; } c; c.u = ((unsigned)b) << 16; return c.f;
}

// ---------------- K1: 3-way bf16 split + squared norms (one wave per row) ----------------
// H layout: [seg(3)][NMAT][NPTS][DIM] bf16 bits
__global__ __launch_bounds__(256) void split_kernel(const float* __restrict__ f1,
                                                    const float* __restrict__ f2,
                                                    unsigned short* __restrict__ H,
                                                    float* __restrict__ sq) {
    const size_t plane = (size_t)NMAT * NPTS * DIM;
    int tid = threadIdx.x;
    int wave = tid >> 6, lane = tid & 63;
    int row = blockIdx.x * 4 + wave;              // 0..16383 = m*NPTS + i
    int m = row >> 10, i = row & (NPTS - 1);
    const float* fr = mat_base(f1, f2, m) + (size_t)i * DIM;
    size_t off = (size_t)m * NPTS * DIM + (size_t)i * DIM;
    float s = 0.f;
    #pragma unroll
    for (int t = 0; t < 4; ++t) {
        int idx = t * 256 + lane * 4;
        float4 v = *(const float4*)&fr[idx];
        s += v.x * v.x + v.y * v.y + v.z * v.z + v.w * v.w;
        unsigned short h1[4], h2[4], h3[4];
        float vv[4] = {v.x, v.y, v.z, v.w};
        #pragma unroll
        for (int c = 0; c < 4; ++c) {
            unsigned short b1 = f2bf_bits(vv[c]);
            float r1 = vv[c] - bfbits2f(b1);
            unsigned short b2 = f2bf_bits(r1);
            float r2 = r1 - bfbits2f(b2);
            unsigned short b3 = f2bf_bits(r2);
            h1[c] = b1; h2[c] = b2; h3[c] = b3;
        }
        *(ushort4*)&H[off + idx]             = *(ushort4*)&h1[0];
        *(ushort4*)&H[plane + off + idx]     = *(ushort4*)&h2[0];
        *(ushort4*)&H[2 * plane + off + idx] = *(ushort4*)&h3[0];
    }
    #pragma unroll
    for (int o = 32; o > 0; o >>= 1) s += __shfl_down(s, o);
    if (lane == 0) sq[row] = s;
}

// ---------------- K2: Gram -> squared distances via bf16 MFMA, 6 split products ----------------
// 128x128 tiles, upper triangle only (mirror stores). 4 waves, each a 64x64 quadrant.
__global__ __launch_bounds__(256) void gram_mfma_kernel(const unsigned short* __restrict__ H,
                                                        const float* __restrict__ sq,
                                                        float* __restrict__ dist) {
    const size_t plane = (size_t)NMAT * NPTS * DIM;
    const size_t msz = (size_t)NPTS * DIM;
    int bid = blockIdx.x;
    int m = bid / 36;
    int t = bid % 36;
    int bi = 0;
    { int a = t; while (a >= 8 - bi) { a -= 8 - bi; ++bi; } t = a; }
    int bj = bi + t;
    int ti = bi << 7, tj = bj << 7;

    __shared__ __align__(16) unsigned short Asl[128 * 32];  // 8KB, [rb(8)][kc(4)][r16(16)][8]
    __shared__ __align__(16) unsigned short Bsl[128 * 32];

    int tid = threadIdx.x;
    int w = tid >> 6, lane = tid & 63;
    int wi = w >> 1, wj = w & 1;
    int r16 = lane & 15, kc = lane >> 4;

    floatx4 acc[4][4];
    #pragma unroll
    for (int a = 0; a < 4; ++a)
        #pragma unroll
        for (int b = 0; b < 4; ++b) acc[a][b] = (floatx4)0.f;

    const int segA[6] = {0, 0, 1, 1, 0, 2};
    const int segB[6] = {0, 1, 0, 1, 2, 0};

    for (int sp = 0; sp < 6; ++sp) {
        const unsigned short* Ag = H + (size_t)segA[sp] * plane + (size_t)m * msz;
        const unsigned short* Bg = H + (size_t)segB[sp] * plane + (size_t)m * msz;
        for (int kk = 0; kk < DIM; kk += 32) {
            __syncthreads();
            #pragma unroll
            for (int s = 0; s < 2; ++s) {
                int rb = w * 2 + s;
                const unsigned short* ga = Ag + (size_t)(ti + rb * 16 + r16) * DIM + kk + kc * 8;
                const unsigned short* gb = Bg + (size_t)(tj + rb * 16 + r16) * DIM + kk + kc * 8;
                __builtin_amdgcn_global_load_lds(
                    (const __attribute__((address_space(1))) void*)ga,
                    (__attribute__((address_space(3))) void*)&Asl[rb * 512], 16, 0, 0);
                __builtin_amdgcn_global_load_lds(
                    (const __attribute__((address_space(1))) void*)gb,
                    (__attribute__((address_space(3))) void*)&Bsl[rb * 512], 16, 0, 0);
            }
            __syncthreads();
            short8 af[4], bf[4];
            #pragma unroll
            for (int a = 0; a < 4; ++a)
                af[a] = *(const short8*)&Asl[(wi * 4 + a) * 512 + lane * 8];
            #pragma unroll
            for (int b = 0; b < 4; ++b)
                bf[b] = *(const short8*)&Bsl[(wj * 4 + b) * 512 + lane * 8];
            #pragma unroll
            for (int a = 0; a < 4; ++a)
                #pragma unroll
                for (int b = 0; b < 4; ++b)
                    acc[a][b] = __builtin_amdgcn_mfma_f32_16x16x32_bf16(af[a], bf[b], acc[a][b], 0, 0, 0);
        }
    }

    const float* sqm = sq + m * NPTS;
    #pragma unroll
    for (int a = 0; a < 4; ++a) {
        int i0 = ti + wi * 64 + a * 16 + (lane >> 4) * 4;
        #pragma unroll
        for (int b = 0; b < 4; ++b) {
            int j = tj + wj * 64 + b * 16 + (lane & 15);
            float sqj = sqm[j];
            #pragma unroll
            for (int r = 0; r < 4; ++r) {
                int i = i0 + r;
                float v = sqm[i] + sqj - 2.f * acc[a][b][r];
                if (i == j) v += 1e10f;
                dist[((size_t)m * NPTS + i) * NPTS + j] = v;
                if (bi != bj) dist[((size_t)m * NPTS + j) * NPTS + i] = v;
            }
        }
    }
}

// ---------------- K3: top-k (k=20 smallest) per row, iterative select-min ----------------
__global__ __launch_bounds__(256) void topk_kernel(const float* __restrict__ dist,
                                                   int* __restrict__ knn_idx) {
    int row = blockIdx.x;                        // m*NPTS + i
    const float* d = dist + (size_t)row * NPTS;
    __shared__ float vals[NPTS];
    __shared__ float cv[4];
    __shared__ int ci[4];
    int tid = threadIdx.x;
    #pragma unroll
    for (int s = 0; s < 4; ++s) vals[tid + s * 256] = d[tid + s * 256];
    __syncthreads();
    for (int sel = 0; sel < KNN; ++sel) {
        float bv = 3e38f; int bi = NPTS;
        #pragma unroll
        for (int s = 0; s < 4; ++s) {
            int j = tid + s * 256;
            float v = vals[j];
            if (v < bv) { bv = v; bi = j; }
        }
        #pragma unroll
        for (int off = 32; off > 0; off >>= 1) {
            float ov = __shfl_down(bv, off);
            int   oi = __shfl_down(bi, off);
            if (ov < bv || (ov == bv && oi < bi)) { bv = ov; bi = oi; }
        }
        if ((tid & 63) == 0) { cv[tid >> 6] = bv; ci[tid >> 6] = bi; }
        __syncthreads();
        if (tid == 0) {
            float fv = cv[0]; int fi = ci[0];
            #pragma unroll
            for (int w = 1; w < 4; ++w)
                if (cv[w] < fv || (cv[w] == fv && ci[w] < fi)) { fv = cv[w]; fi = ci[w]; }
            knn_idx[(size_t)row * KNN + sel] = fi;
            vals[fi] = 3e38f;
        }
        __syncthreads();
    }
}

// ---------------- K4a: x + sum of neighbor features (D=1024) ----------------
__global__ __launch_bounds__(256) void hsum_big_kernel(const float* __restrict__ f1,
                                                       const float* __restrict__ f2,
                                                       const int* __restrict__ knn_idx,
                                                       float* __restrict__ hsum) {
    int row = blockIdx.x;
    int m = row >> 10, i = row & (NPTS - 1);
    const float* f = mat_base(f1, f2, m);
    __shared__ int nb[KNN];
    int tid = threadIdx.x;
    if (tid < KNN) nb[tid] = knn_idx[(size_t)row * KNN + tid];
    __syncthreads();
    int c = tid * 4;
    float4 acc = *(const float4*)&f[(size_t)i * DIM + c];
    #pragma unroll
    for (int t = 0; t < KNN; ++t) {
        float4 v = *(const float4*)&f[(size_t)nb[t] * DIM + c];
        acc.x += v.x; acc.y += v.y; acc.z += v.z; acc.w += v.w;
    }
    *(float4*)&hsum[(size_t)row * DIM + c] = acc;
}

// ---------------- K5a: x + sum of neighbor features (H=64), one wave per row ----------------
__global__ __launch_bounds__(256) void hsum_small_kernel(const float* __restrict__ h,
                                                         const int* __restrict__ knn_idx,
                                                         float* __restrict__ outp) {
    int tid = threadIdx.x;
    int wave = tid >> 6, lane = tid & 63;
    int row = blockIdx.x * 4 + wave;
    int m = row >> 10;
    const int* nb = knn_idx + (size_t)row * KNN;
    const float* hm = h + (size_t)m * NPTS * HID;
    float acc = h[(size_t)row * HID + lane];
    #pragma unroll
    for (int t = 0; t < KNN; ++t)
        acc += hm[(size_t)nb[t] * HID + lane];
    outp[(size_t)row * HID + lane] = acc;
}

// ---------------- MLP GEMM: C[i][h] = act(sum_d A[i][d]*W[d][h] + b[h]) ----------------
template <int DIN, bool RELU>
__global__ __launch_bounds__(256) void mlp_gemm_kernel(const float* __restrict__ A,
                                                       const float* __restrict__ W,
                                                       const float* __restrict__ bias,
                                                       float* __restrict__ C) {
    int row0 = blockIdx.x * 64;
    __shared__ float As[64][20];
    __shared__ float Ws[16][HID];
    int tid = threadIdx.x;
    int ty = tid >> 4, tx = tid & 15;
    float acc[4][4];
    #pragma unroll
    for (int i = 0; i < 4; ++i)
        #pragma unroll
        for (int j = 0; j < 4; ++j) acc[i][j] = 0.f;
    for (int kk = 0; kk < DIN; kk += 16) {
        {
            int r = tid >> 2, c = (tid & 3) * 4;
            *(float4*)&As[r][c] = *(const float4*)&A[(size_t)(row0 + r) * DIN + kk + c];
        }
        {
            int d = tid >> 4, hh = (tid & 15) * 4;
            *(float4*)&Ws[d][hh] = *(const float4*)&W[(size_t)(kk + d) * HID + hh];
        }
        __syncthreads();
        #pragma unroll
        for (int k = 0; k < 16; ++k) {
            float a[4];
            #pragma unroll
            for (int ii = 0; ii < 4; ++ii) a[ii] = As[ty * 4 + ii][k];
            float4 w = *(const float4*)&Ws[k][tx * 4];
            #pragma unroll
            for (int ii = 0; ii < 4; ++ii) {
                acc[ii][0] += a[ii] * w.x;
                acc[ii][1] += a[ii] * w.y;
                acc[ii][2] += a[ii] * w.z;
                acc[ii][3] += a[ii] * w.w;
            }
        }
        __syncthreads();
    }
    #pragma unroll
    for (int ii = 0; ii < 4; ++ii) {
        int r = row0 + ty * 4 + ii;
        float o[4];
        #pragma unroll
        for (int jj = 0; jj < 4; ++jj) {
            float v = acc[ii][jj] + bias[tx * 4 + jj];
            if (RELU) v = fmaxf(v, 0.f);
            o[jj] = v;
        }
        *(float4*)&C[(size_t)r * HID + tx * 4] = *(float4*)&o[0];
    }
}

// ---------------- K6a: sim = z1 @ z2^T (64x64 tiles, K=64) ----------------
__global__ __launch_bounds__(256) void sim_kernel(const float* __restrict__ z,
                                                  float* __restrict__ logits) {
    int bid = blockIdx.x;
    int b = bid >> 8;
    int tile = bid & 255;
    int ti = (tile >> 4) << 6;
    int tj = (tile & 15) << 6;
    const float* z1 = z + (size_t)b * NPTS * HID;
    const float* z2 = z + (size_t)(BATCH + b) * NPTS * HID;
    __shared__ float Z1[64][68];
    __shared__ float Z2[64][68];
    int tid = threadIdx.x;
    #pragma unroll
    for (int i = 0; i < 4; ++i) {
        int l = tid + i * 256;
        int r = l >> 4, c = (l & 15) * 4;
        *(float4*)&Z1[r][c] = *(const float4*)&z1[(size_t)(ti + r) * HID + c];
        *(float4*)&Z2[r][c] = *(const float4*)&z2[(size_t)(tj + r) * HID + c];
    }
    __syncthreads();
    int ty = tid >> 4, tx = tid & 15;
    float acc[4][4];
    #pragma unroll
    for (int i = 0; i < 4; ++i)
        #pragma unroll
        for (int j = 0; j < 4; ++j) acc[i][j] = 0.f;
    #pragma unroll
    for (int h = 0; h < HID; ++h) {
        float a[4], bb[4];
        #pragma unroll
        for (int ii = 0; ii < 4; ++ii) { a[ii] = Z1[ty * 4 + ii][h]; bb[ii] = Z2[tx * 4 + ii][h]; }
        #pragma unroll
        for (int ii = 0; ii < 4; ++ii)
            #pragma unroll
            for (int jj = 0; jj < 4; ++jj)
                acc[ii][jj] += a[ii] * bb[jj];
    }
    #pragma unroll
    for (int ii = 0; ii < 4; ++ii) {
        float* dst = logits + ((size_t)b * NPTS + ti + ty * 4 + ii) * NPTS + tj + tx * 4;
        *(float4*)&dst[0] = *(float4*)&acc[ii][0];
    }
}

// ---------------- K6b: row softmax ----------------
__global__ __launch_bounds__(256) void softmax_kernel(const float* __restrict__ logits,
                                                      float* __restrict__ out) {
    int row = blockIdx.x;                         // 0..8191
    const float* L = logits + (size_t)row * NPTS;
    __shared__ float buf[NPTS];
    __shared__ float red[8];
    int tid = threadIdx.x;
    int wave = tid >> 6, lane = tid & 63;
    float mx = -3e38f;
    #pragma unroll
    for (int s = 0; s < 4; ++s) {
        float v = L[tid + s * 256];
        buf[tid + s * 256] = v;
        mx = fmaxf(mx, v);
    }
    #pragma unroll
    for (int off = 32; off > 0; off >>= 1) mx = fmaxf(mx, __shfl_down(mx, off));
    if (lane == 0) red[wave] = mx;
    __syncthreads();
    mx = fmaxf(fmaxf(red[0], red[1]), fmaxf(red[2], red[3]));
    float sum = 0.f;
    #pragma unroll
    for (int s = 0; s < 4; ++s) {
        float e = expf(buf[tid + s * 256] - mx);
        buf[tid + s * 256] = e;
        sum += e;
    }
    #pragma unroll
    for (int off = 32; off > 0; off >>= 1) sum += __shfl_down(sum, off);
    if (lane == 0) red[4 + wave] = sum;
    __syncthreads();
    float inv = 1.f / (red[4] + red[5] + red[6] + red[7]);
    #pragma unroll
    for (int s = 0; s < 4; ++s)
        out[(size_t)row * NPTS + tid + s * 256] = buf[tid + s * 256] * inv;
}

extern "C" void kernel_launch(void* const* d_in, const int* in_sizes, int n_in,
                              void* d_out, int out_size, void* d_ws, size_t ws_size,
                              hipStream_t stream) {
    const float* f1  = (const float*)d_in[0];
    const float* f2  = (const float*)d_in[1];
    const float* W1a = (const float*)d_in[2];
    const float* b1a = (const float*)d_in[3];
    const float* W2a = (const float*)d_in[4];
    const float* b2a = (const float*)d_in[5];
    const float* W1b = (const float*)d_in[6];
    const float* b1b = (const float*)d_in[7];
    const float* W2b = (const float*)d_in[8];
    const float* b2b = (const float*)d_in[9];
    float* out = (float*)d_out;

    // workspace layout (16B-aligned segments):
    // H (3*16*1024*1024 bf16 = 100.7MB) | dist (67.1MB, reused: dist->hsum->logits)
    // | sq | kidx | bufA | bufB
    char* ws = (char*)d_ws;
    unsigned short* H = (unsigned short*)ws;
    float* dist = (float*)(ws + (size_t)3 * NMAT * NPTS * DIM * sizeof(unsigned short));
    float* sq   = dist + (size_t)NMAT * NPTS * NPTS;
    int*   kidx = (int*)(sq + NMAT * NPTS);
    float* bufA = (float*)(kidx + NMAT * NPTS * KNN);
    float* bufB = bufA + (size_t)NMAT * NPTS * HID;

    split_kernel<<<NMAT * NPTS / 4, 256, 0, stream>>>(f1, f2, H, sq);
    gram_mfma_kernel<<<NMAT * 36, 256, 0, stream>>>(H, sq, dist);
    topk_kernel<<<NMAT * NPTS, 256, 0, stream>>>(dist, kidx);
    hsum_big_kernel<<<NMAT * NPTS, 256, 0, stream>>>(f1, f2, kidx, dist);       // dist := hsum
    mlp_gemm_kernel<DIM, true><<<NMAT * NPTS / 64, 256, 0, stream>>>(dist, W1a, b1a, bufA);
    mlp_gemm_kernel<HID, false><<<NMAT * NPTS / 64, 256, 0, stream>>>(bufA, W2a, b2a, bufB);
    hsum_small_kernel<<<NMAT * NPTS / 4, 256, 0, stream>>>(bufB, kidx, bufA);
    mlp_gemm_kernel<HID, true><<<NMAT * NPTS / 64, 256, 0, stream>>>(bufA, W1b, b1b, bufB);
    mlp_gemm_kernel<HID, false><<<NMAT * NPTS / 64, 256, 0, stream>>>(bufB, W2b, b2b, bufA);
    sim_kernel<<<BATCH * 256, 256, 0, stream>>>(bufA, dist);                    // dist := logits
    softmax_kernel<<<BATCH * NPTS, 256, 0, stream>>>(dist, out);
}

// Round 4
// 734.132 us; speedup vs baseline: 1.4797x; 1.1866x over previous
//
#include <hip/hip_runtime.h>
#include <hip/hip_bf16.h>
#include <math.h>

#define BATCH 8
#define NPTS  1024
#define DIM   1024
#define HID   64
#define KNN   20
#define NMAT  16
#define KPACK 3072   // 3 bf16 segments stored contiguously per row: k = seg*1024 + d

typedef __attribute__((ext_vector_type(8))) short short8;
typedef __attribute__((ext_vector_type(4))) float floatx4;

__device__ __forceinline__ const float* mat_base(const float* f1, const float* f2, int m) {
    return (m < BATCH) ? (f1 + (size_t)m * NPTS * DIM)
                       : (f2 + (size_t)(m - BATCH) * NPTS * DIM);
}

__device__ __forceinline__ unsigned short f2bf_bits(float v) {
    __hip_bfloat16 h = __float2bfloat16(v);   // RNE
    return *(unsigned short*)&h;
}
__device__ __forceinline__ float bfbits2f(unsigned short b) {
    union { unsigned u; float f; } c; c.u = ((unsigned)b) << 16; return c.f;
}

// ---------------- K1: 3-way bf16 split (segments packed per row) + squared norms ----------------
__global__ __launch_bounds__(256) void split_kernel(const float* __restrict__ f1,
                                                    const float* __restrict__ f2,
                                                    unsigned short* __restrict__ H,
                                                    float* __restrict__ sq) {
    int tid = threadIdx.x;
    int wave = tid >> 6, lane = tid & 63;
    int row = blockIdx.x * 4 + wave;              // 0..16383 = m*NPTS + i
    int m = row >> 10, i = row & (NPTS - 1);
    const float* fr = mat_base(f1, f2, m) + (size_t)i * DIM;
    unsigned short* Hr = H + (size_t)row * KPACK;
    float s = 0.f;
    #pragma unroll
    for (int t = 0; t < 4; ++t) {
        int idx = t * 256 + lane * 4;
        float4 v = *(const float4*)&fr[idx];
        s += v.x * v.x + v.y * v.y + v.z * v.z + v.w * v.w;
        unsigned short h1[4], h2[4], h3[4];
        float vv[4] = {v.x, v.y, v.z, v.w};
        #pragma unroll
        for (int c = 0; c < 4; ++c) {
            unsigned short b1 = f2bf_bits(vv[c]);
            float r1 = vv[c] - bfbits2f(b1);
            unsigned short b2 = f2bf_bits(r1);
            float r2 = r1 - bfbits2f(b2);
            unsigned short b3 = f2bf_bits(r2);
            h1[c] = b1; h2[c] = b2; h3[c] = b3;
        }
        *(ushort4*)&Hr[idx]        = *(ushort4*)&h1[0];
        *(ushort4*)&Hr[1024 + idx] = *(ushort4*)&h2[0];
        *(ushort4*)&Hr[2048 + idx] = *(ushort4*)&h3[0];
    }
    #pragma unroll
    for (int o = 32; o > 0; o >>= 1) s += __shfl_down(s, o);
    if (lane == 0) sq[row] = s;
}

// ---------------- K2: Gram -> squared distances via bf16 MFMA ----------------
// 6 segment-pair passes (same products & accumulation order as the verified R2
// kernel -> bitwise-identical dist). 128x128 upper-triangle tiles, mirror stores.
// XCD-pinned swizzle: all 36 tiles of a matrix on one XCD for L2 reuse.
__global__ __launch_bounds__(256) void gram_mfma_kernel(const unsigned short* __restrict__ H,
                                                        const float* __restrict__ sq,
                                                        float* __restrict__ dist) {
    int bid = blockIdx.x;
    int xcd = bid & 7;
    int g = bid >> 3;                 // 0..71
    int m = xcd + 8 * (g >= 36);
    int t = (g >= 36) ? g - 36 : g;
    int bi = 0;
    { int a = t; while (a >= 8 - bi) { a -= 8 - bi; ++bi; } t = a; }
    int bj = bi + t;
    int ti = bi << 7, tj = bj << 7;

    const unsigned short* Hm = H + (size_t)m * NPTS * KPACK;

    // [chunk(16)=rb*2+kb][lane(64)][8 shorts] ; BK=64 per iteration
    __shared__ __align__(16) unsigned short Asl[16 * 512];   // 16KB
    __shared__ __align__(16) unsigned short Bsl[16 * 512];

    int tid = threadIdx.x;
    int w = tid >> 6, lane = tid & 63;
    int wi = w >> 1, wj = w & 1;
    int r16 = lane & 15, kc = lane >> 4;

    floatx4 acc[4][4];
    #pragma unroll
    for (int a = 0; a < 4; ++a)
        #pragma unroll
        for (int b = 0; b < 4; ++b) acc[a][b] = (floatx4)0.f;

    // products (h1h1),(h1h2),(h2h1),(h2h2),(h1h3),(h3h1) — cross terms REQUIRED:
    // a K-concatenated single pass only yields segment-diagonal products (R3 bug).
    const int segA[6] = {0, 0, 1, 1, 0, 2};
    const int segB[6] = {0, 1, 0, 1, 2, 0};

    #pragma unroll
    for (int sp = 0; sp < 6; ++sp) {
        const int aBase = segA[sp] << 10;
        const int bBase = segB[sp] << 10;
        for (int kk = 0; kk < 1024; kk += 64) {
            __syncthreads();
            #pragma unroll
            for (int c = 0; c < 4; ++c) {
                int ca = w * 4 + c;
                int rb = ca >> 1, kb = ca & 1;
                const unsigned short* ga = Hm + (size_t)(ti + rb * 16 + r16) * KPACK + aBase + kk + kb * 32 + kc * 8;
                const unsigned short* gb = Hm + (size_t)(tj + rb * 16 + r16) * KPACK + bBase + kk + kb * 32 + kc * 8;
                __builtin_amdgcn_global_load_lds(
                    (const __attribute__((address_space(1))) void*)ga,
                    (__attribute__((address_space(3))) void*)&Asl[ca * 512], 16, 0, 0);
                __builtin_amdgcn_global_load_lds(
                    (const __attribute__((address_space(1))) void*)gb,
                    (__attribute__((address_space(3))) void*)&Bsl[ca * 512], 16, 0, 0);
            }
            __syncthreads();
            short8 af[2][4], bf[2][4];
            #pragma unroll
            for (int kb = 0; kb < 2; ++kb) {
                #pragma unroll
                for (int a = 0; a < 4; ++a)
                    af[kb][a] = *(const short8*)&Asl[((wi * 4 + a) * 2 + kb) * 512 + lane * 8];
                #pragma unroll
                for (int b = 0; b < 4; ++b)
                    bf[kb][b] = *(const short8*)&Bsl[((wj * 4 + b) * 2 + kb) * 512 + lane * 8];
            }
            #pragma unroll
            for (int kb = 0; kb < 2; ++kb)
                #pragma unroll
                for (int a = 0; a < 4; ++a)
                    #pragma unroll
                    for (int b = 0; b < 4; ++b)
                        acc[a][b] = __builtin_amdgcn_mfma_f32_16x16x32_bf16(af[kb][a], bf[kb][b], acc[a][b], 0, 0, 0);
        }
    }

    const float* sqm = sq + m * NPTS;
    #pragma unroll
    for (int a = 0; a < 4; ++a) {
        int i0 = ti + wi * 64 + a * 16 + (lane >> 4) * 4;
        #pragma unroll
        for (int b = 0; b < 4; ++b) {
            int j = tj + wj * 64 + b * 16 + (lane & 15);
            float sqj = sqm[j];
            #pragma unroll
            for (int r = 0; r < 4; ++r) {
                int i = i0 + r;
                float v = sqm[i] + sqj - 2.f * acc[a][b][r];
                if (i == j) v += 1e10f;
                dist[((size_t)m * NPTS + i) * NPTS + j] = v;
                if (bi != bj) dist[((size_t)m * NPTS + j) * NPTS + i] = v;
            }
        }
    }
}

// ---------------- K3: top-k (k=20 smallest), one wave per row, all-register ----------------
__global__ __launch_bounds__(256) void topk_kernel(const float* __restrict__ dist,
                                                   int* __restrict__ knn_idx) {
    int tid = threadIdx.x;
    int wave = tid >> 6, lane = tid & 63;
    int row = blockIdx.x * 4 + wave;
    const float* d = dist + (size_t)row * NPTS;
    float v[16];
    #pragma unroll
    for (int s = 0; s < 16; ++s) v[s] = d[s * 64 + lane];
    int myj = 0;
    for (int sel = 0; sel < KNN; ++sel) {
        float bv = v[0]; int bs = 0;
        #pragma unroll
        for (int s = 1; s < 16; ++s)
            if (v[s] < bv) { bv = v[s]; bs = s; }   // ascending s: lowest j locally on ties
        int bj = bs * 64 + lane;
        #pragma unroll
        for (int off = 1; off < 64; off <<= 1) {
            float ov = __shfl_xor(bv, off);
            int   oj = __shfl_xor(bj, off);
            if (ov < bv || (ov == bv && oj < bj)) { bv = ov; bj = oj; }
        }
        // all lanes agree on winner (bv, bj)
        if ((bj & 63) == lane) v[bj >> 6] = 3e38f;  // owner clears
        if (lane == sel) myj = bj;
    }
    if (lane < KNN) knn_idx[(size_t)row * KNN + lane] = myj;
}

// ---------------- K4a: x + sum of neighbor features (D=1024), XCD-swizzled ----------------
__global__ __launch_bounds__(256) void hsum_big_kernel(const float* __restrict__ f1,
                                                       const float* __restrict__ f2,
                                                       const int* __restrict__ knn_idx,
                                                       float* __restrict__ hsum) {
    int bid = blockIdx.x;
    int xcd = bid & 7;
    int g = bid >> 3;                  // 0..2047
    int m = xcd + 8 * (g >> 10);
    int i = g & 1023;
    int row = m * NPTS + i;
    const float* f = mat_base(f1, f2, m);
    __shared__ int nb[KNN];
    int tid = threadIdx.x;
    if (tid < KNN) nb[tid] = knn_idx[(size_t)row * KNN + tid];
    __syncthreads();
    int c = tid * 4;
    float4 acc = *(const float4*)&f[(size_t)i * DIM + c];
    #pragma unroll
    for (int t = 0; t < KNN; ++t) {
        float4 v = *(const float4*)&f[(size_t)nb[t] * DIM + c];
        acc.x += v.x; acc.y += v.y; acc.z += v.z; acc.w += v.w;
    }
    *(float4*)&hsum[(size_t)row * DIM + c] = acc;
}

// ---------------- K5a: x + sum of neighbor features (H=64), one wave per row ----------------
__global__ __launch_bounds__(256) void hsum_small_kernel(const float* __restrict__ h,
                                                         const int* __restrict__ knn_idx,
                                                         float* __restrict__ outp) {
    int tid = threadIdx.x;
    int wave = tid >> 6, lane = tid & 63;
    int row = blockIdx.x * 4 + wave;
    int m = row >> 10;
    const int* nb = knn_idx + (size_t)row * KNN;
    const float* hm = h + (size_t)m * NPTS * HID;
    float acc = h[(size_t)row * HID + lane];
    #pragma unroll
    for (int t = 0; t < KNN; ++t)
        acc += hm[(size_t)nb[t] * HID + lane];
    outp[(size_t)row * HID + lane] = acc;
}

// ---------------- MLP GEMM: C[i][h] = act(sum_d A[i][d]*W[d][h] + b[h]) ----------------
template <int DIN, bool RELU>
__global__ __launch_bounds__(256) void mlp_gemm_kernel(const float* __restrict__ A,
                                                       const float* __restrict__ W,
                                                       const float* __restrict__ bias,
                                                       float* __restrict__ C) {
    int row0 = blockIdx.x * 64;
    __shared__ float As[64][20];
    __shared__ float Ws[16][HID];
    int tid = threadIdx.x;
    int ty = tid >> 4, tx = tid & 15;
    float acc[4][4];
    #pragma unroll
    for (int i = 0; i < 4; ++i)
        #pragma unroll
        for (int j = 0; j < 4; ++j) acc[i][j] = 0.f;
    for (int kk = 0; kk < DIN; kk += 16) {
        {
            int r = tid >> 2, c = (tid & 3) * 4;
            *(float4*)&As[r][c] = *(const float4*)&A[(size_t)(row0 + r) * DIN + kk + c];
        }
        {
            int d = tid >> 4, hh = (tid & 15) * 4;
            *(float4*)&Ws[d][hh] = *(const float4*)&W[(size_t)(kk + d) * HID + hh];
        }
        __syncthreads();
        #pragma unroll
        for (int k = 0; k < 16; ++k) {
            float a[4];
            #pragma unroll
            for (int ii = 0; ii < 4; ++ii) a[ii] = As[ty * 4 + ii][k];
            float4 w = *(const float4*)&Ws[k][tx * 4];
            #pragma unroll
            for (int ii = 0; ii < 4; ++ii) {
                acc[ii][0] += a[ii] * w.x;
                acc[ii][1] += a[ii] * w.y;
                acc[ii][2] += a[ii] * w.z;
                acc[ii][3] += a[ii] * w.w;
            }
        }
        __syncthreads();
    }
    #pragma unroll
    for (int ii = 0; ii < 4; ++ii) {
        int r = row0 + ty * 4 + ii;
        float o[4];
        #pragma unroll
        for (int jj = 0; jj < 4; ++jj) {
            float v = acc[ii][jj] + bias[tx * 4 + jj];
            if (RELU) v = fmaxf(v, 0.f);
            o[jj] = v;
        }
        *(float4*)&C[(size_t)r * HID + tx * 4] = *(float4*)&o[0];
    }
}

// ---------------- K6a: sim = z1 @ z2^T (64x64 tiles, K=64) ----------------
__global__ __launch_bounds__(256) void sim_kernel(const float* __restrict__ z,
                                                  float* __restrict__ logits) {
    int bid = blockIdx.x;
    int b = bid >> 8;
    int tile = bid & 255;
    int ti = (tile >> 4) << 6;
    int tj = (tile & 15) << 6;
    const float* z1 = z + (size_t)b * NPTS * HID;
    const float* z2 = z + (size_t)(BATCH + b) * NPTS * HID;
    __shared__ float Z1[64][68];
    __shared__ float Z2[64][68];
    int tid = threadIdx.x;
    #pragma unroll
    for (int i = 0; i < 4; ++i) {
        int l = tid + i * 256;
        int r = l >> 4, c = (l & 15) * 4;
        *(float4*)&Z1[r][c] = *(const float4*)&z1[(size_t)(ti + r) * HID + c];
        *(float4*)&Z2[r][c] = *(const float4*)&z2[(size_t)(tj + r) * HID + c];
    }
    __syncthreads();
    int ty = tid >> 4, tx = tid & 15;
    float acc[4][4];
    #pragma unroll
    for (int i = 0; i < 4; ++i)
        #pragma unroll
        for (int j = 0; j < 4; ++j) acc[i][j] = 0.f;
    #pragma unroll
    for (int h = 0; h < HID; ++h) {
        float a[4], bb[4];
        #pragma unroll
        for (int ii = 0; ii < 4; ++ii) { a[ii] = Z1[ty * 4 + ii][h]; bb[ii] = Z2[tx * 4 + ii][h]; }
        #pragma unroll
        for (int ii = 0; ii < 4; ++ii)
            #pragma unroll
            for (int jj = 0; jj < 4; ++jj)
                acc[ii][jj] += a[ii] * bb[jj];
    }
    #pragma unroll
    for (int ii = 0; ii < 4; ++ii) {
        float* dst = logits + ((size_t)b * NPTS + ti + ty * 4 + ii) * NPTS + tj + tx * 4;
        *(float4*)&dst[0] = *(float4*)&acc[ii][0];
    }
}

// ---------------- K6b: row softmax ----------------
__global__ __launch_bounds__(256) void softmax_kernel(const float* __restrict__ logits,
                                                      float* __restrict__ out) {
    int row = blockIdx.x;                         // 0..8191
    const float* L = logits + (size_t)row * NPTS;
    __shared__ float buf[NPTS];
    __shared__ float red[8];
    int tid = threadIdx.x;
    int wave = tid >> 6, lane = tid & 63;
    float mx = -3e38f;
    #pragma unroll
    for (int s = 0; s < 4; ++s) {
        float v = L[tid + s * 256];
        buf[tid + s * 256] = v;
        mx = fmaxf(mx, v);
    }
    #pragma unroll
    for (int off = 32; off > 0; off >>= 1) mx = fmaxf(mx, __shfl_down(mx, off));
    if (lane == 0) red[wave] = mx;
    __syncthreads();
    mx = fmaxf(fmaxf(red[0], red[1]), fmaxf(red[2], red[3]));
    float sum = 0.f;
    #pragma unroll
    for (int s = 0; s < 4; ++s) {
        float e = expf(buf[tid + s * 256] - mx);
        buf[tid + s * 256] = e;
        sum += e;
    }
    #pragma unroll
    for (int off = 32; off > 0; off >>= 1) sum += __shfl_down(sum, off);
    if (lane == 0) red[4 + wave] = sum;
    __syncthreads();
    float inv = 1.f / (red[4] + red[5] + red[6] + red[7]);
    #pragma unroll
    for (int s = 0; s < 4; ++s)
        out[(size_t)row * NPTS + tid + s * 256] = buf[tid + s * 256] * inv;
}

extern "C" void kernel_launch(void* const* d_in, const int* in_sizes, int n_in,
                              void* d_out, int out_size, void* d_ws, size_t ws_size,
                              hipStream_t stream) {
    const float* f1  = (const float*)d_in[0];
    const float* f2  = (const float*)d_in[1];
    const float* W1a = (const float*)d_in[2];
    const float* b1a = (const float*)d_in[3];
    const float* W2a = (const float*)d_in[4];
    const float* b2a = (const float*)d_in[5];
    const float* W1b = (const float*)d_in[6];
    const float* b1b = (const float*)d_in[7];
    const float* W2b = (const float*)d_in[8];
    const float* b2b = (const float*)d_in[9];
    float* out = (float*)d_out;

    // workspace: H packed (100.7MB) | dist (67.1MB, reused: dist->hsum->logits) | sq | kidx | bufA | bufB
    char* ws = (char*)d_ws;
    unsigned short* H = (unsigned short*)ws;
    float* dist = (float*)(ws + (size_t)NMAT * NPTS * KPACK * sizeof(unsigned short));
    float* sq   = dist + (size_t)NMAT * NPTS * NPTS;
    int*   kidx = (int*)(sq + NMAT * NPTS);
    float* bufA = (float*)(kidx + NMAT * NPTS * KNN);
    float* bufB = bufA + (size_t)NMAT * NPTS * HID;

    split_kernel<<<NMAT * NPTS / 4, 256, 0, stream>>>(f1, f2, H, sq);
    gram_mfma_kernel<<<NMAT * 36, 256, 0, stream>>>(H, sq, dist);
    topk_kernel<<<NMAT * NPTS / 4, 256, 0, stream>>>(dist, kidx);
    hsum_big_kernel<<<NMAT * NPTS, 256, 0, stream>>>(f1, f2, kidx, dist);       // dist := hsum
    mlp_gemm_kernel<DIM, true><<<NMAT * NPTS / 64, 256, 0, stream>>>(dist, W1a, b1a, bufA);
    mlp_gemm_kernel<HID, false><<<NMAT * NPTS / 64, 256, 0, stream>>>(bufA, W2a, b2a, bufB);
    hsum_small_kernel<<<NMAT * NPTS / 4, 256, 0, stream>>>(bufB, kidx, bufA);
    mlp_gemm_kernel<HID, true><<<NMAT * NPTS / 64, 256, 0, stream>>>(bufA, W1b, b1b, bufB);
    mlp_gemm_kernel<HID, false><<<NMAT * NPTS / 64, 256, 0, stream>>>(bufB, W2b, b2b, bufA);
    sim_kernel<<<BATCH * 256, 256, 0, stream>>>(bufA, dist);                    // dist := logits
    softmax_kernel<<<BATCH * NPTS, 256, 0, stream>>>(dist, out);
}